// Round 4
// baseline (228.339 us; speedup 1.0000x reference)
//
#include <hip/hip_runtime.h>

// x [B,C,H,W] fp32, guide [B,1,H,W] fp32.
// out[b,c,h,t] = max_{j<=t} x[b,c,h,j]*guide[b,0,h,j]  (cummax along W)
#define PB 8
#define PC 256
#define PH 128
#define PW 128
#define TOTAL_ROWS (PB * PC * PH)                // 262144
#define ROWS_PER_SEG 4
#define ROW_GROUPS (TOTAL_ROWS / ROWS_PER_SEG)   // 65536
#define NITER 4
#define SEGS (ROW_GROUPS / NITER)                // 16384 resident segments
#define KSTRIDE ((size_t)(PH * PW / 4))          // row stride in vfloat4

typedef float vfloat4 __attribute__((ext_vector_type(4)));

// R3 post-mortem: persistent 2-deep pipeline (R3) == one-shot (R0/R2) == ~65us
// ~= 4.1 TB/s. MLP/duty-cycle are not the limiter (160KB in flight per CU vs
// ~9KB needed). R1 counters: WRITE_SIZE = 146MB >= full output despite a
// 256MB L3 -> the NT stores forced every output byte to HBM during the
// kernel, finely interleaved with the read stream (HBM read<->write
// turnaround thrash). Fill (write-only, cached) = 6.7 TB/s; copy ubench
// (cached stores, L2 write-combine burst drain) = 6.3 TB/s; our NT mix =
// 4.1. This round: SINGLE variable — all non-temporal hints removed, plain
// cached loads/stores; let L2/L3 absorb the output and drain in bursts.
struct Seg {
    vfloat4 x0, x1, x2, x3;   // four channel-adjacent rows (share one guide)
    vfloat4 g;
};

__device__ __forceinline__ void seg_load(Seg& s, const float* __restrict__ x,
                                         const float* __restrict__ guide,
                                         int rg, int sub)
{
    const int h  = rg & (PH - 1);
    const int g4 = rg >> 7;            // b*64 + c4
    const int b  = rg >> 13;
    const size_t xoff = (((size_t)g4 << 2) * PH + h) * PW + sub * 4;
    const size_t goff = ((size_t)b * PH + h) * PW + sub * 4;
    const vfloat4* xp = (const vfloat4*)(x + xoff);
    // 4 independent x streams + 1 cached guide — all on the cached path.
    s.x0 = xp[0];
    s.x1 = xp[KSTRIDE];
    s.x2 = xp[2 * KSTRIDE];
    s.x3 = xp[3 * KSTRIDE];
    s.g  = *(const vfloat4*)(guide + goff);
}

__device__ __forceinline__ void seg_cs(const Seg& s, float* __restrict__ out,
                                       int rg, int sub)
{
    const int h  = rg & (PH - 1);
    const int g4 = rg >> 7;
    const size_t xoff = (((size_t)g4 << 2) * PH + h) * PW + sub * 4;
    vfloat4* op = (vfloat4*)(out + xoff);

    vfloat4 ov0, ov1, ov2, ov3;
    float t0, t1, t2, t3;

    // Local inclusive max-scan over each lane's 4 owned elems, per row.
    ov0.x = s.x0.x * s.g.x;
    ov0.y = fmaxf(ov0.x, s.x0.y * s.g.y);
    ov0.z = fmaxf(ov0.y, s.x0.z * s.g.z);
    ov0.w = fmaxf(ov0.z, s.x0.w * s.g.w);
    t0 = ov0.w;
    ov1.x = s.x1.x * s.g.x;
    ov1.y = fmaxf(ov1.x, s.x1.y * s.g.y);
    ov1.z = fmaxf(ov1.y, s.x1.z * s.g.z);
    ov1.w = fmaxf(ov1.z, s.x1.w * s.g.w);
    t1 = ov1.w;
    ov2.x = s.x2.x * s.g.x;
    ov2.y = fmaxf(ov2.x, s.x2.y * s.g.y);
    ov2.z = fmaxf(ov2.y, s.x2.z * s.g.z);
    ov2.w = fmaxf(ov2.z, s.x2.w * s.g.w);
    t2 = ov2.w;
    ov3.x = s.x3.x * s.g.x;
    ov3.y = fmaxf(ov3.x, s.x3.y * s.g.y);
    ov3.z = fmaxf(ov3.y, s.x3.z * s.g.z);
    ov3.w = fmaxf(ov3.z, s.x3.w * s.g.w);
    t3 = ov3.w;

    // Four interleaved branchless 32-lane inclusive max-scans.
    // __shfl_up below the segment floor returns own value; fmax(x,x)==x.
    #pragma unroll
    for (int d = 1; d < 32; d <<= 1) {
        float u0 = __shfl_up(t0, d, 32);
        float u1 = __shfl_up(t1, d, 32);
        float u2 = __shfl_up(t2, d, 32);
        float u3 = __shfl_up(t3, d, 32);
        t0 = fmaxf(t0, u0);
        t1 = fmaxf(t1, u1);
        t2 = fmaxf(t2, u2);
        t3 = fmaxf(t3, u3);
    }

    float p0 = __shfl_up(t0, 1, 32);
    float p1 = __shfl_up(t1, 1, 32);
    float p2 = __shfl_up(t2, 1, 32);
    float p3 = __shfl_up(t3, 1, 32);
    if (sub == 0) {                      // v_cndmask, no branch
        p0 = -__builtin_inff(); p1 = -__builtin_inff();
        p2 = -__builtin_inff(); p3 = -__builtin_inff();
    }
    ov0.x = fmaxf(ov0.x, p0); ov0.y = fmaxf(ov0.y, p0);
    ov0.z = fmaxf(ov0.z, p0); ov0.w = fmaxf(ov0.w, p0);
    ov1.x = fmaxf(ov1.x, p1); ov1.y = fmaxf(ov1.y, p1);
    ov1.z = fmaxf(ov1.z, p1); ov1.w = fmaxf(ov1.w, p1);
    ov2.x = fmaxf(ov2.x, p2); ov2.y = fmaxf(ov2.y, p2);
    ov2.z = fmaxf(ov2.z, p2); ov2.w = fmaxf(ov2.w, p2);
    ov3.x = fmaxf(ov3.x, p3); ov3.y = fmaxf(ov3.y, p3);
    ov3.z = fmaxf(ov3.z, p3); ov3.w = fmaxf(ov3.w, p3);

    // Plain cached stores: L2/L3 absorb and burst-drain.
    op[0]           = ov0;
    op[KSTRIDE]     = ov1;
    op[2 * KSTRIDE] = ov2;
    op[3 * KSTRIDE] = ov3;
}

__global__ __launch_bounds__(256) void i5pool_cummax_kernel(
    const float* __restrict__ x,
    const float* __restrict__ guide,
    float* __restrict__ out)
{
    const int tid = blockIdx.x * blockDim.x + threadIdx.x;
    const int sub = tid & 31;          // lane-within-row (owns elems 4*sub..)
    const int s0  = tid >> 5;          // resident segment id, 0..SEGS-1

    Seg A, B;
    // Software pipeline, hand-unrolled (all buffer refs static — rule #20):
    seg_load(A, x, guide, s0,            sub);   // iter 0 in flight
    seg_load(B, x, guide, s0 + SEGS,     sub);   // iter 1 in flight
    seg_cs(A, out, s0,            sub);          // counted vmcnt wait only
    seg_load(A, x, guide, s0 + 2 * SEGS, sub);   // iter 2 in flight
    seg_cs(B, out, s0 + SEGS,     sub);
    seg_load(B, x, guide, s0 + 3 * SEGS, sub);   // iter 3 in flight
    seg_cs(A, out, s0 + 2 * SEGS, sub);
    seg_cs(B, out, s0 + 3 * SEGS, sub);
}

extern "C" void kernel_launch(void* const* d_in, const int* in_sizes, int n_in,
                              void* d_out, int out_size, void* d_ws, size_t ws_size,
                              hipStream_t stream) {
    const float* x     = (const float*)d_in[0];
    const float* guide = (const float*)d_in[1];
    float* out = (float*)d_out;

    // SEGS segments * 32 lanes = 524288 threads -> 2048 blocks (8 per CU),
    // each segment loops over NITER=4 row-groups with a 2-deep pipeline.
    const int total_threads = SEGS * 32;
    const int block = 256;
    const int grid = total_threads / block;  // 2048

    i5pool_cummax_kernel<<<grid, block, 0, stream>>>(x, guide, out);
}

// Round 5
// 226.161 us; speedup vs baseline: 1.0096x; 1.0096x over previous
//
#include <hip/hip_runtime.h>

// x [B,C,H,W] fp32, guide [B,1,H,W] fp32.
// out[b,c,h,t] = max_{j<=t} x[b,c,h,j]*guide[b,0,h,j]  (cummax along W)
#define PB 8
#define PC 256
#define PH 128
#define PW 128
#define TOTAL_ROWS (PB * PC * PH)        // 262144
#define NBLK 2048                        // 8 blocks/CU, all resident
#define BLOCK 256
#define SEGS_PER_BLOCK (BLOCK / 32)      // 8 rows per block per iteration
#define NITER (TOTAL_ROWS / (NBLK * SEGS_PER_BLOCK))   // 16

typedef float vfloat4 __attribute__((ext_vector_type(4)));

// R4 post-mortem: cached stores REGRESSED (~73us vs NT ~65.5us) -> NT wins;
// and R0==R2==R3 killed the schedule/MLP/duty-cycle theories. The one
// remaining structural difference vs the 6.5 TB/s fill / 6.3 TB/s copy is
// FRONTIER COMPACTNESS: previous kernels kept ~8K discontiguous 8KB chunks
// (4 channel-rows 64KB apart per block, row-groups scattered) = tens of
// thousands of open DRAM row streams. This version is copy-shaped: one row
// per 32-lane segment, consecutive segments -> consecutive rows,
// consecutive blocks -> consecutive 4KB, grid-stride over 16 iterations so
// the chip sweeps x and out as two contiguous 8MB bands in address order.
// Guide re-read per row, but per-iteration guide working set is 64KB ->
// L2-resident, negligible HBM traffic. NT x loads + NT stores (best-known
// config), cached guide, 2-deep A/B register prefetch.
struct Seg {
    vfloat4 xv;
    vfloat4 gv;
};

__device__ __forceinline__ void seg_load(Seg& s, const float* __restrict__ x,
                                         const float* __restrict__ guide,
                                         int row, int sub)
{
    const int h = row & (PH - 1);
    const int b = row >> 15;             // row / (PC*PH)
    const size_t xoff = (size_t)row * PW + sub * 4;
    const size_t goff = (((size_t)b << 7) + h) * PW + sub * 4;
    s.xv = __builtin_nontemporal_load((const vfloat4*)(x + xoff));
    s.gv = *(const vfloat4*)(guide + goff);
}

__device__ __forceinline__ void seg_cs(const Seg& s, float* __restrict__ out,
                                       int row, int sub)
{
    // Local inclusive max-scan over the lane's 4 elems.
    float e0 = s.xv.x * s.gv.x;
    float e1 = fmaxf(e0, s.xv.y * s.gv.y);
    float e2 = fmaxf(e1, s.xv.z * s.gv.z);
    float e3 = fmaxf(e2, s.xv.w * s.gv.w);

    // Branchless 32-lane inclusive max-scan of lane totals (width=32 keeps
    // the two rows of a wave64 in separate segments). __shfl_up below the
    // segment floor returns own value; fmax(x,x)==x.
    float t = e3;
    #pragma unroll
    for (int d = 1; d < 32; d <<= 1) {
        float u = __shfl_up(t, d, 32);
        t = fmaxf(t, u);
    }
    float pre = __shfl_up(t, 1, 32);
    if (sub == 0) pre = -__builtin_inff();   // v_cndmask, no branch

    vfloat4 ov;
    ov.x = fmaxf(e0, pre);
    ov.y = fmaxf(e1, pre);
    ov.z = fmaxf(e2, pre);
    ov.w = fmaxf(e3, pre);

    const size_t xoff = (size_t)row * PW + sub * 4;
    __builtin_nontemporal_store(ov, (vfloat4*)(out + xoff));
}

__global__ __launch_bounds__(BLOCK) void i5pool_cummax_kernel(
    const float* __restrict__ x,
    const float* __restrict__ guide,
    float* __restrict__ out)
{
    const int sub = threadIdx.x & 31;          // lane within row segment
    const int seg = threadIdx.x >> 5;          // 0..7, row offset in block
    const int bl  = blockIdx.x;

    // Row for iteration i: contiguous chip-wide band advancing in order.
    //   row(i) = (i*NBLK + bl)*SEGS_PER_BLOCK + seg
    const int rbase = bl * SEGS_PER_BLOCK + seg;
    const int rstep = NBLK * SEGS_PER_BLOCK;   // 16384 rows per iteration

    Seg A, B;
    seg_load(A, x, guide, rbase,         sub);   // iter 0 in flight
    seg_load(B, x, guide, rbase + rstep, sub);   // iter 1 in flight

    // 2-deep software pipeline, all buffer refs static (rule #20).
    #pragma unroll
    for (int it = 0; it < NITER / 2 - 1; ++it) {
        const int r0 = rbase + (2 * it) * rstep;
        seg_cs(A, out, r0, sub);
        seg_load(A, x, guide, r0 + 2 * rstep, sub);
        seg_cs(B, out, r0 + rstep, sub);
        seg_load(B, x, guide, r0 + 3 * rstep, sub);
    }
    const int rl = rbase + (NITER - 2) * rstep;
    seg_cs(A, out, rl, sub);
    seg_cs(B, out, rl + rstep, sub);
}

extern "C" void kernel_launch(void* const* d_in, const int* in_sizes, int n_in,
                              void* d_out, int out_size, void* d_ws, size_t ws_size,
                              hipStream_t stream) {
    const float* x     = (const float*)d_in[0];
    const float* guide = (const float*)d_in[1];
    float* out = (float*)d_out;

    // 2048 blocks x 256 threads = 32 waves/CU, all resident in one dispatch;
    // each 32-lane segment sweeps 16 rows in chip-contiguous order.
    i5pool_cummax_kernel<<<NBLK, BLOCK, 0, stream>>>(x, guide, out);
}

// Round 7
// 225.455 us; speedup vs baseline: 1.0128x; 1.0031x over previous
//
#include <hip/hip_runtime.h>

// x [B,C,H,W] fp32, guide [B,1,H,W] fp32.
// out[b,c,h,t] = max_{j<=t} x[b,c,h,j]*guide[b,0,h,j]  (cummax along W)
#define PB 8
#define PC 256
#define PH 128
#define PW 128
#define TOTAL_ROWS (PB * PC * PH)      // 262144
#define ROWS_PER_THREAD 4
#define ROW_GROUPS (TOTAL_ROWS / ROWS_PER_THREAD)  // 65536

typedef float vfloat4 __attribute__((ext_vector_type(4)));

// R6 was an infra failure (container died twice); resubmitting R5's kernel
// unchanged — the hypothesis is still untested.
// R5 post-mortem: contiguous copy-shaped sweep (71us) did NOT beat the
// scattered 4-row NT version (65.3us) -> frontier compactness irrelevant.
// Full matrix now missing exactly one cell: CACHED loads + NT stores.
// Evidence it matters: R1 (the only run with kernel counters, cached
// x-loads) showed FETCH_SIZE=65.8MB for a 129MB read set -- L3 served half
// the input. NT loads carry no-allocate hints that may forfeit those L3
// hits; R4 tested cached loads but paired them with cached stores, which
// independently cost ~8us (dirty-writeback interleave), masking the gain.
// This round: R2's exact structure (best known, 65.3us), ONE change --
// x loads cached, stores stay NT.
__global__ __launch_bounds__(256, 8) void i5pool_cummax_kernel(
    const float* __restrict__ x,
    const float* __restrict__ guide,
    float* __restrict__ out)
{
    const int tid = blockIdx.x * blockDim.x + threadIdx.x;
    const int sub = tid & 31;          // lane-within-row (owns elems 4*sub..)
    const int rg  = tid >> 5;          // row group, 0..ROW_GROUPS-1

    // rg = (b*64 + c4)*128 + h ; rows are (b*256 + 4*c4 + k)*128 + h
    const int h = rg & (PH - 1);
    const int g = rg >> 7;             // b*64 + c4
    const int b = rg >> 13;

    const size_t row0  = ((size_t)(g << 2)) * PH + h;      // row index, k=0
    const size_t xoff  = row0 * PW + sub * 4;              // k stride = PH*PW
    const size_t goff  = ((size_t)b * PH + h) * PW + sub * 4;

    const vfloat4* xp = (const vfloat4*)(x + xoff);
    vfloat4*       op = (vfloat4*)(out + xoff);
    const size_t kstride = (size_t)PH * PW / 4;            // in vfloat4 units

    // Issue all loads up front: 4 independent CACHED x streams (L3 can
    // serve resident lines) + 1 cached guide (reused by 256 channels).
    vfloat4 xv[ROWS_PER_THREAD];
    #pragma unroll
    for (int k = 0; k < ROWS_PER_THREAD; ++k)
        xv[k] = xp[k * kstride];
    const vfloat4 gv = *(const vfloat4*)(guide + goff);

    // Local inclusive max-scan over each lane's 4 elems; tot[k] = lane max.
    vfloat4 ov[ROWS_PER_THREAD];
    float  tot[ROWS_PER_THREAD];
    #pragma unroll
    for (int k = 0; k < ROWS_PER_THREAD; ++k) {
        float e0 = xv[k].x * gv.x;
        float e1 = fmaxf(e0, xv[k].y * gv.y);
        float e2 = fmaxf(e1, xv[k].z * gv.z);
        float e3 = fmaxf(e2, xv[k].w * gv.w);
        ov[k].x = e0; ov[k].y = e1; ov[k].z = e2; ov[k].w = e3;
        tot[k] = e3;
    }

    // Four interleaved branchless 32-lane inclusive max-scans.
    // __shfl_up below the segment floor returns own value; fmax(x,x)==x.
    #pragma unroll
    for (int d = 1; d < 32; d <<= 1) {
        float t0 = __shfl_up(tot[0], d, 32);
        float t1 = __shfl_up(tot[1], d, 32);
        float t2 = __shfl_up(tot[2], d, 32);
        float t3 = __shfl_up(tot[3], d, 32);
        tot[0] = fmaxf(tot[0], t0);
        tot[1] = fmaxf(tot[1], t1);
        tot[2] = fmaxf(tot[2], t2);
        tot[3] = fmaxf(tot[3], t3);
    }

    #pragma unroll
    for (int k = 0; k < ROWS_PER_THREAD; ++k) {
        float pre = __shfl_up(tot[k], 1, 32);
        if (sub == 0) pre = -__builtin_inff();   // v_cndmask, no branch
        ov[k].x = fmaxf(ov[k].x, pre);
        ov[k].y = fmaxf(ov[k].y, pre);
        ov[k].z = fmaxf(ov[k].z, pre);
        ov[k].w = fmaxf(ov[k].w, pre);
    }

    // NT stores: proven ~8us faster than cached (R2 vs R4).
    #pragma unroll
    for (int k = 0; k < ROWS_PER_THREAD; ++k)
        __builtin_nontemporal_store(ov[k], op + k * kstride);
}

extern "C" void kernel_launch(void* const* d_in, const int* in_sizes, int n_in,
                              void* d_out, int out_size, void* d_ws, size_t ws_size,
                              hipStream_t stream) {
    const float* x     = (const float*)d_in[0];
    const float* guide = (const float*)d_in[1];
    float* out = (float*)d_out;

    // ROW_GROUPS row-quads, 32 lanes each -> 2,097,152 threads
    const int total_threads = ROW_GROUPS * 32;
    const int block = 256;
    const int grid = total_threads / block;  // 8192

    i5pool_cummax_kernel<<<grid, block, 0, stream>>>(x, guide, out);
}

// Round 8
// 219.030 us; speedup vs baseline: 1.0425x; 1.0293x over previous
//
#include <hip/hip_runtime.h>

// x [B,C,H,W] fp32, guide [B,1,H,W] fp32.
// out[b,c,h,t] = max_{j<=t} x[b,c,h,j]*guide[b,0,h,j]  (cummax along W)
#define PB 8
#define PC 256
#define PH 128
#define PW 128
#define TOTAL_ROWS (PB * PC * PH)      // 262144
#define ROWS_PER_THREAD 4
#define ROW_GROUPS (TOTAL_ROWS / ROWS_PER_THREAD)  // 65536

typedef float vfloat4 __attribute__((ext_vector_type(4)));

// FINAL (revert to R2, the best-measured config: kernel ~65.3us).
// Completed config matrix (kernel-us via fixed-overhead decomposition):
//   R2 one-shot NT/NT 4-chan-rows        65.3  <- best
//   R3 persistent-pipelined, same        65.7  (duty-cycle theory: dead)
//   R4 cached/cached                     73.1  (store-policy: NT wins)
//   R5 contiguous copy-shaped sweep      71.0  (frontier theory: dead)
//   R7 cached-loads/NT-stores            70.3  (load-policy: NT wins)
// All on-chip pipes idle (VALUBusy 7%, bank-conflict 0, occ 72%); the op
// runs at ~4.1 TB/s for its compulsory 269MB mixed 1:1 read:write stream
// vs 6.8 TB/s write-only fill on the same harness. No remaining HIP-level
// lever changed it; this is the practical ceiling for this access mix.
__global__ __launch_bounds__(256, 8) void i5pool_cummax_kernel(
    const float* __restrict__ x,
    const float* __restrict__ guide,
    float* __restrict__ out)
{
    const int tid = blockIdx.x * blockDim.x + threadIdx.x;
    const int sub = tid & 31;          // lane-within-row (owns elems 4*sub..)
    const int rg  = tid >> 5;          // row group, 0..ROW_GROUPS-1

    // rg = (b*64 + c4)*128 + h ; rows are (b*256 + 4*c4 + k)*128 + h
    const int h = rg & (PH - 1);
    const int g = rg >> 7;             // b*64 + c4
    const int b = rg >> 13;

    const size_t row0  = ((size_t)(g << 2)) * PH + h;      // row index, k=0
    const size_t xoff  = row0 * PW + sub * 4;              // k stride = PH*PW
    const size_t goff  = ((size_t)b * PH + h) * PW + sub * 4;

    const vfloat4* xp = (const vfloat4*)(x + xoff);
    vfloat4*       op = (vfloat4*)(out + xoff);
    const size_t kstride = (size_t)PH * PW / 4;            // in vfloat4 units

    // 4 independent NT x streams (evict-first, pure streaming; nt still
    // probes caches so L3-resident lines hit) + 1 cached guide (reused by
    // 256 channels).
    vfloat4 xv[ROWS_PER_THREAD];
    #pragma unroll
    for (int k = 0; k < ROWS_PER_THREAD; ++k)
        xv[k] = __builtin_nontemporal_load(xp + k * kstride);
    const vfloat4 gv = *(const vfloat4*)(guide + goff);

    // Local inclusive max-scan over each lane's 4 elems; tot[k] = lane max.
    vfloat4 ov[ROWS_PER_THREAD];
    float  tot[ROWS_PER_THREAD];
    #pragma unroll
    for (int k = 0; k < ROWS_PER_THREAD; ++k) {
        float e0 = xv[k].x * gv.x;
        float e1 = fmaxf(e0, xv[k].y * gv.y);
        float e2 = fmaxf(e1, xv[k].z * gv.z);
        float e3 = fmaxf(e2, xv[k].w * gv.w);
        ov[k].x = e0; ov[k].y = e1; ov[k].z = e2; ov[k].w = e3;
        tot[k] = e3;
    }

    // Four interleaved branchless 32-lane inclusive max-scans.
    // __shfl_up below the segment floor returns own value; fmax(x,x)==x.
    #pragma unroll
    for (int d = 1; d < 32; d <<= 1) {
        float t0 = __shfl_up(tot[0], d, 32);
        float t1 = __shfl_up(tot[1], d, 32);
        float t2 = __shfl_up(tot[2], d, 32);
        float t3 = __shfl_up(tot[3], d, 32);
        tot[0] = fmaxf(tot[0], t0);
        tot[1] = fmaxf(tot[1], t1);
        tot[2] = fmaxf(tot[2], t2);
        tot[3] = fmaxf(tot[3], t3);
    }

    #pragma unroll
    for (int k = 0; k < ROWS_PER_THREAD; ++k) {
        float pre = __shfl_up(tot[k], 1, 32);
        if (sub == 0) pre = -__builtin_inff();   // v_cndmask, no branch
        ov[k].x = fmaxf(ov[k].x, pre);
        ov[k].y = fmaxf(ov[k].y, pre);
        ov[k].z = fmaxf(ov[k].z, pre);
        ov[k].w = fmaxf(ov[k].w, pre);
    }

    // NT stores: proven faster than cached (R2 65.3 vs R4 73.1).
    #pragma unroll
    for (int k = 0; k < ROWS_PER_THREAD; ++k)
        __builtin_nontemporal_store(ov[k], op + k * kstride);
}

extern "C" void kernel_launch(void* const* d_in, const int* in_sizes, int n_in,
                              void* d_out, int out_size, void* d_ws, size_t ws_size,
                              hipStream_t stream) {
    const float* x     = (const float*)d_in[0];
    const float* guide = (const float*)d_in[1];
    float* out = (float*)d_out;

    // ROW_GROUPS row-quads, 32 lanes each -> 2,097,152 threads
    const int total_threads = ROW_GROUPS * 32;
    const int block = 256;
    const int grid = total_threads / block;  // 8192

    i5pool_cummax_kernel<<<grid, block, 0, stream>>>(x, guide, out);
}